// Round 17
// baseline (4539.770 us; speedup 1.0000x reference)
//
#include <hip/hip_runtime.h>
#include <math.h>

#define FEAT 1024
#define NB 16       // batch
#define NT 256      // seq len
#define VOCAB 32000
#define G3 3072     // 3*FEAT
#define NWG 256     // scan blocks
#define FLAG_STRIDE 32   // 128B between flags
#define NGRP 8
#define GSZ 32
#define NXPT 24     // n-tiles per xp m-tile (G3/128)
#define DLY 32      // layer-1 pipeline delay (steps)
#define CHAIN (NT + DLY)

#define BK 32       // K-step of the MFMA GEMM
#define LDH 40      // f16 row stride in LDS
#define SMEM_BYTES 63104   // scan: W0 48K + red 12.75K + sums/bias; >= gemm 40K

typedef float f4 __attribute__((ext_vector_type(4)));
typedef float f32x4 __attribute__((ext_vector_type(4)));
typedef _Float16 half4v __attribute__((ext_vector_type(4)));
typedef _Float16 half8v __attribute__((ext_vector_type(8)));

// ---------------- embedding gather ----------------
__global__ __launch_bounds__(256) void gather_kernel(const int* __restrict__ x,
                                                     const float* __restrict__ emb,
                                                     float* __restrict__ xs) {
    int row = blockIdx.x;
    int t = row >> 4;
    int b = row & 15;
    int tok = x[b * NT + t];
    const float4* src = (const float4*)(emb + (size_t)tok * FEAT);
    float4* dst = (float4*)(xs + (size_t)row * FEAT);
    dst[threadIdx.x] = src[threadIdx.x];
}

// ---------------- agent-coherent store (LLC) ----------------
__device__ __forceinline__ void store_f32_sc(float* p, float v) {
    asm volatile("global_store_dword %0, %1, off sc0 sc1" :: "v"(p), "v"(v) : "memory");
}
// verified 2-hop barrier primitives (round 10/13/14)
__device__ __forceinline__ void bar_arrive(unsigned* flag, unsigned expected) {
    asm volatile("s_waitcnt vmcnt(0)\n\t"
                 "global_store_dword %0, %1, off sc0 sc1"
                 :: "v"(flag), "v"(expected) : "memory");
}
__device__ __forceinline__ void bar_poll(const unsigned* p, unsigned expected) {
    unsigned v; int spins = 0;
    while (true) {
        asm volatile("global_load_dword %0, %1, off sc0 sc1\n\t"
                     "s_waitcnt vmcnt(0)"
                     : "=&v"(v) : "v"(p) : "memory");
        if (v >= expected) break;
        if (++spins > (1 << 20)) break;   // safety valve
        __builtin_amdgcn_s_sleep(1);
    }
}

// ---------------- split-f16 MFMA GEMM tile (verified body) ----------
__device__ __forceinline__ void gemm_tile(char* smemraw,
        const float* __restrict__ A, const float* __restrict__ Bm,
        const float* __restrict__ bias, float* __restrict__ C,
        int N, int K, int m_t, int n_t, int perm,
        int coherent, unsigned* cnt) {
    _Float16* AhS = (_Float16*)smemraw;
    _Float16* AlS = AhS + 128 * LDH;
    _Float16* BhS = AlS + 128 * LDH;
    _Float16* BlS = BhS + 128 * LDH;

    int tid = threadIdx.x;
    int srow = tid >> 1;
    int shf = tid & 1;

    const float* aptr = A + (size_t)(m_t * 128 + srow) * K + shf * 16;
    const float* bptr = Bm + (size_t)(n_t * 128 + srow) * K + shf * 16;

    int wid = tid >> 6;
    int wr = wid >> 1, wc = wid & 1;
    int lane = tid & 63;
    int fr = lane & 15;
    int ke = lane >> 4;

    f32x4 acc[4][4];
#pragma unroll
    for (int i = 0; i < 4; i++)
#pragma unroll
        for (int j = 0; j < 4; j++) acc[i][j] = (f32x4){0.f, 0.f, 0.f, 0.f};

    float4 a4[4], b4[4];
#pragma unroll
    for (int q = 0; q < 4; q++) {
        a4[q] = *(const float4*)(aptr + q * 4);
        b4[q] = *(const float4*)(bptr + q * 4);
    }

    for (int k0 = 0; k0 < K; k0 += BK) {
        __syncthreads();
#pragma unroll
        for (int q = 0; q < 4; q++) {
            half4v hh, hl;
            hh.x = (_Float16)a4[q].x; hl.x = (_Float16)(a4[q].x - (float)hh.x);
            hh.y = (_Float16)a4[q].y; hl.y = (_Float16)(a4[q].y - (float)hh.y);
            hh.z = (_Float16)a4[q].z; hl.z = (_Float16)(a4[q].z - (float)hh.z);
            hh.w = (_Float16)a4[q].w; hl.w = (_Float16)(a4[q].w - (float)hh.w);
            int o = srow * LDH + shf * 16 + q * 4;
            *(half4v*)&AhS[o] = hh;
            *(half4v*)&AlS[o] = hl;
            half4v gh, gl;
            gh.x = (_Float16)b4[q].x; gl.x = (_Float16)(b4[q].x - (float)gh.x);
            gh.y = (_Float16)b4[q].y; gl.y = (_Float16)(b4[q].y - (float)gh.y);
            gh.z = (_Float16)b4[q].z; gl.z = (_Float16)(b4[q].z - (float)gh.z);
            gh.w = (_Float16)b4[q].w; gl.w = (_Float16)(b4[q].w - (float)gh.w);
            *(half4v*)&BhS[o] = gh;
            *(half4v*)&BlS[o] = gl;
        }
        __syncthreads();

        if (k0 + BK < K) {
#pragma unroll
            for (int q = 0; q < 4; q++) {
                a4[q] = *(const float4*)(aptr + k0 + BK + q * 4);
                b4[q] = *(const float4*)(bptr + k0 + BK + q * 4);
            }
        }

        half8v ah[4], al[4], bh[4], bl[4];
#pragma unroll
        for (int i = 0; i < 4; i++) {
            int ao = (wr * 64 + i * 16 + fr) * LDH + ke * 8;
            ah[i] = *(const half8v*)&AhS[ao];
            al[i] = *(const half8v*)&AlS[ao];
            int bo = (wc * 64 + i * 16 + fr) * LDH + ke * 8;
            bh[i] = *(const half8v*)&BhS[bo];
            bl[i] = *(const half8v*)&BlS[bo];
        }
#pragma unroll
        for (int i = 0; i < 4; i++)
#pragma unroll
            for (int j = 0; j < 4; j++) {
                acc[i][j] = __builtin_amdgcn_mfma_f32_16x16x32_f16(ah[i], bh[j], acc[i][j], 0, 0, 0);
                acc[i][j] = __builtin_amdgcn_mfma_f32_16x16x32_f16(ah[i], bl[j], acc[i][j], 0, 0, 0);
                acc[i][j] = __builtin_amdgcn_mfma_f32_16x16x32_f16(al[i], bh[j], acc[i][j], 0, 0, 0);
            }
    }

#pragma unroll
    for (int j = 0; j < 4; j++) {
        int col = n_t * 128 + wc * 64 + j * 16 + fr;
        float bv = bias[col];
#pragma unroll
        for (int i = 0; i < 4; i++) {
#pragma unroll
            for (int v = 0; v < 4; v++) {
                int mrow = m_t * 128 + wr * 64 + i * 16 + 4 * ke + v;
                int orow = perm ? (((mrow & 15) << 8) | (mrow >> 4)) : mrow;
                float val = acc[i][j][v] + bv;
                if (coherent) store_f32_sc(&C[(size_t)orow * N + col], val);
                else          C[(size_t)orow * N + col] = val;
            }
        }
    }
    if (cnt) {
        asm volatile("s_waitcnt vmcnt(0)" ::: "memory");
        __syncthreads();
        if (tid == 0)
            __hip_atomic_fetch_add(cnt, 1u, __ATOMIC_RELAXED, __HIP_MEMORY_SCOPE_AGENT);
    }
}

// ---------------- standalone decoder GEMM (verified round 6+) ----------------
__global__ __launch_bounds__(256, 2) void gemm_split16(
        const float* __restrict__ A, const float* __restrict__ Bm,
        const float* __restrict__ bias, float* __restrict__ C,
        int N, int K, int GM, int perm) {
    __shared__ __align__(16) char smem[4 * 128 * LDH * 2];
    int nNt = N >> 7;
    int perGroup = GM * nNt;
    int g = blockIdx.x / perGroup;
    int rix = blockIdx.x % perGroup;
    int n_t = rix / GM;
    int m_t = g * GM + (rix % GM);
    gemm_tile(smem, A, Bm, bias, C, N, K, m_t, n_t, perm, 0, nullptr);
}

// ================ combined two-layer chain scan =================
// Chain step s: L0 computes h0(s) (s<NT); L1 computes h1(t1=s-DLY) (s>=DLY).
// ONE barrier per step; 288 steps replace 512. W0 in LDS; W1 streamed (L2-hot,
// same 48KB/block every step). xp1 overwrites xp in place (sc1 writethrough by
// GEMM tiles, gated on gflags>=8(m+1) -- r14-verified); L1 reads xp1 + h1-ring
// via sc1 (scan L2s hold stale xp0/xs copies of those lines). ys1 = xs ring:
// safe because xpcnt[m]==24 (all xs reads done) precedes chain step 8m <= t1,
// and ys1[t1] is written at step t1+DLY.
__device__ __forceinline__ void scan_chain(char* smemraw,
        float* __restrict__ xp, const float* __restrict__ Whh0,
        const float* __restrict__ bhh0, const float* __restrict__ Whh1,
        const float* __restrict__ bhh1, const float* __restrict__ h0all,
        float* __restrict__ ys0, float* __restrict__ ys1,
        float* __restrict__ hid,
        unsigned* __restrict__ flags, unsigned* __restrict__ gflags,
        const unsigned* __restrict__ xpcnt, const unsigned* __restrict__ xp1cnt) {
    float* w_lds = (float*)smemraw;          // 12*1024 (W0)
    float* red   = w_lds + 12 * 1024;        // 192*17
    float* sums  = red + 192 * 17;           // 192
    float* b0l   = sums + 192;               // 12
    float* b1l   = b0l + 12;                 // 12

    __builtin_amdgcn_s_setprio(1);

    int wg = blockIdx.x;
    int j0 = wg * 4;
    int tid = threadIdx.x;

    for (int rr = 0; rr < 12; rr++) {
        int gate = rr >> 2, jloc = rr & 3;
        int grow = gate * FEAT + j0 + jloc;
        float4 v = ((const float4*)(Whh0 + (size_t)grow * FEAT))[tid];
        *(float4*)(w_lds + rr * 1024 + tid * 4) = v;
    }
    if (tid < 12) {
        int gate = tid >> 2, jloc = tid & 3;
        b0l[tid] = bhh0[gate * FEAT + j0 + jloc];
        b1l[tid] = bhh1[gate * FEAT + j0 + jloc];
    }
    if (tid == 0) bar_poll(&xpcnt[0], NXPT);   // xp0 rows for t=0 ready
    __syncthreads();

    int bg = tid >> 6;        // 0..3 batch group
    int kc = tid & 63;        // 0..63 k chunk
    int pb = tid >> 2, pjl = tid & 3, pj = j0 + pjl;   // gating map (tid<64)

    // W1 gate-base pointers (streamed rows, L2-hot)
    const float* w1g0 = Whh1 + (size_t)j0 * FEAT;
    const float* w1g1 = Whh1 + (size_t)(FEAT + j0) * FEAT;
    const float* w1g2 = Whh1 + (size_t)(2 * FEAT + j0) * FEAT;

    float hreg0 = 0.f, hreg1 = 0.f;
    if (tid < 64) {
        hreg0 = h0all[pb * FEAT + pj];
        hreg1 = h0all[NB * FEAT + pb * FEAT + pj];
    }

    for (int s = 0; s < CHAIN; s++) {
        int do0 = (s < NT);
        int t1 = s - DLY;
        int do1 = (t1 >= 0);

        // L0 xp gate vals (plain; xp0 rows virgin for this block's L2)
        float xr = 0.f, xz = 0.f, xnv = 0.f;
        if (do0 && tid < 64) {
            const float* xpr = xp + (size_t)(s * NB + pb) * G3;
            xr = xpr[pj]; xz = xpr[FEAT + pj]; xnv = xpr[2 * FEAT + pj];
        }
        // L1 xp1 gate vals: sc1 issue-only (drained by h1 batch's vmcnt(0))
        float x1r, x1z, x1n;
        if (do1 && tid < 64) {
            const float* xpr = xp + (size_t)(t1 * NB + pb) * G3;
            asm volatile(
                "global_load_dword %0, %3, off sc0 sc1\n\t"
                "global_load_dword %1, %4, off sc0 sc1\n\t"
                "global_load_dword %2, %5, off sc0 sc1"
                : "=&v"(x1r), "=&v"(x1z), "=&v"(x1n)
                : "v"(xpr + pj), "v"(xpr + FEAT + pj), "v"(xpr + 2 * FEAT + pj)
                : "memory");
        }

        // ================= layer 0 =================
        if (do0) {
            const float* hc = (s == 0) ? h0all : (ys0 + (size_t)(s - 1) * NB * FEAT);
            f4 h4[16];
#pragma unroll
            for (int bi = 0; bi < 4; bi++) {
                const float* hp = hc + (size_t)(bg * 4 + bi) * FEAT + kc * 4;
#pragma unroll
                for (int q = 0; q < 4; q++)
                    h4[bi * 4 + q] = *(const f4*)(hp + q * 256);
            }
            float part[48];
#pragma unroll
            for (int i = 0; i < 48; i++) part[i] = 0.f;
#pragma unroll
            for (int q = 0; q < 4; q++) {
                int kof = q * 256 + kc * 4;
#pragma unroll
                for (int rr = 0; rr < 12; rr++) {
                    f4 w = *(const f4*)&w_lds[rr * 1024 + kof];
#pragma unroll
                    for (int bi = 0; bi < 4; bi++) {
                        f4 h = h4[bi * 4 + q];
                        float p = part[rr * 4 + bi];
                        p = fmaf(h.x, w.x, p); p = fmaf(h.y, w.y, p);
                        p = fmaf(h.z, w.z, p); p = fmaf(h.w, w.w, p);
                        part[rr * 4 + bi] = p;
                    }
                }
            }
#pragma unroll
            for (int i = 0; i < 48; i++) {
                part[i] += __shfl_xor(part[i], 1);
                part[i] += __shfl_xor(part[i], 2);
            }
            if ((kc & 3) == 0) {
#pragma unroll
                for (int rr = 0; rr < 12; rr++)
#pragma unroll
                    for (int bi = 0; bi < 4; bi++)
                        red[(rr * 16 + bg * 4 + bi) * 17 + (kc >> 2)] = part[rr * 4 + bi];
            }
        }
        __syncthreads();
        if (do0 && tid < 192) {
            float sm = 0.f;
#pragma unroll
            for (int c = 0; c < 16; c++) sm += red[tid * 17 + c];
            sums[tid] = sm;
        }
        __syncthreads();
        if (do0 && tid < 64) {
            float dr = sums[pjl * 16 + pb] + b0l[pjl];
            float dz = sums[(4 + pjl) * 16 + pb] + b0l[4 + pjl];
            float dn = sums[(8 + pjl) * 16 + pb] + b0l[8 + pjl];
            float r = 1.f / (1.f + expf(-(xr + dr)));
            float z = 1.f / (1.f + expf(-(xz + dz)));
            float n = tanhf(xnv + r * dn);
            float hv = (1.f - z) * n + z * hreg0;
            hreg0 = hv;
            store_f32_sc(ys0 + (size_t)(s * NB + pb) * FEAT + pj, hv);
            if (s == NT - 1) hid[pb * FEAT + pj] = hv;
        }

        // ================= layer 1 =================
        if (do1) {
            // h1(t1-1) via sc1 batch (bypass stale L2; drains xp1 scalars too)
            const float* hc1 = (t1 == 0) ? (h0all + NB * FEAT)
                                         : (ys1 + (size_t)(t1 - 1) * NB * FEAT);
            f4 h4[16];
            {
                const float* p0 = hc1 + (size_t)(bg * 4 + 0) * FEAT + kc * 4;
                const float* p1 = hc1 + (size_t)(bg * 4 + 1) * FEAT + kc * 4;
                const float* p2 = hc1 + (size_t)(bg * 4 + 2) * FEAT + kc * 4;
                const float* p3 = hc1 + (size_t)(bg * 4 + 3) * FEAT + kc * 4;
                asm volatile(
                    "global_load_dwordx4 %0,  %16, off sc0 sc1\n\t"
                    "global_load_dwordx4 %1,  %16, off offset:1024 sc0 sc1\n\t"
                    "global_load_dwordx4 %2,  %16, off offset:2048 sc0 sc1\n\t"
                    "global_load_dwordx4 %3,  %16, off offset:3072 sc0 sc1\n\t"
                    "global_load_dwordx4 %4,  %17, off sc0 sc1\n\t"
                    "global_load_dwordx4 %5,  %17, off offset:1024 sc0 sc1\n\t"
                    "global_load_dwordx4 %6,  %17, off offset:2048 sc0 sc1\n\t"
                    "global_load_dwordx4 %7,  %17, off offset:3072 sc0 sc1\n\t"
                    "global_load_dwordx4 %8,  %18, off sc0 sc1\n\t"
                    "global_load_dwordx4 %9,  %18, off offset:1024 sc0 sc1\n\t"
                    "global_load_dwordx4 %10, %18, off offset:2048 sc0 sc1\n\t"
                    "global_load_dwordx4 %11, %18, off offset:3072 sc0 sc1\n\t"
                    "global_load_dwordx4 %12, %19, off sc0 sc1\n\t"
                    "global_load_dwordx4 %13, %19, off offset:1024 sc0 sc1\n\t"
                    "global_load_dwordx4 %14, %19, off offset:2048 sc0 sc1\n\t"
                    "global_load_dwordx4 %15, %19, off offset:3072 sc0 sc1\n\t"
                    "s_waitcnt vmcnt(0)"
                    : "=&v"(h4[0]), "=&v"(h4[1]), "=&v"(h4[2]), "=&v"(h4[3]),
                      "=&v"(h4[4]), "=&v"(h4[5]), "=&v"(h4[6]), "=&v"(h4[7]),
                      "=&v"(h4[8]), "=&v"(h4[9]), "=&v"(h4[10]), "=&v"(h4[11]),
                      "=&v"(h4[12]), "=&v"(h4[13]), "=&v"(h4[14]), "=&v"(h4[15])
                    : "v"(p0), "v"(p1), "v"(p2), "v"(p3) : "memory");
                __builtin_amdgcn_sched_barrier(0);
            }
            float part[48];
#pragma unroll
            for (int i = 0; i < 48; i++) part[i] = 0.f;
#pragma unroll
            for (int q = 0; q < 4; q++) {
                int kof = q * 256 + kc * 4;
#pragma unroll
                for (int jl = 0; jl < 4; jl++) {
                    f4 w0v = *(const f4*)(w1g0 + (size_t)jl * FEAT + kof);
                    f4 w1v = *(const f4*)(w1g1 + (size_t)jl * FEAT + kof);
                    f4 w2v = *(const f4*)(w1g2 + (size_t)jl * FEAT + kof);
#pragma unroll
                    for (int bi = 0; bi < 4; bi++) {
                        f4 h = h4[bi * 4 + q];
                        float p = part[jl * 4 + bi];
                        p = fmaf(h.x, w0v.x, p); p = fmaf(h.y, w0v.y, p);
                        p = fmaf(h.z, w0v.z, p); p = fmaf(h.w, w0v.w, p);
                        part[jl * 4 + bi] = p;
                        p = part[(4 + jl) * 4 + bi];
                        p = fmaf(h.x, w1v.x, p); p = fmaf(h.y, w1v.y, p);
                        p = fmaf(h.z, w1v.z, p); p = fmaf(h.w, w1v.w, p);
                        part[(4 + jl) * 4 + bi] = p;
                        p = part[(8 + jl) * 4 + bi];
                        p = fmaf(h.x, w2v.x, p); p = fmaf(h.y, w2v.y, p);
                        p = fmaf(h.z, w2v.z, p); p = fmaf(h.w, w2v.w, p);
                        p = part[(8 + jl) * 4 + bi] = p;
                    }
                }
            }
#pragma unroll
            for (int i = 0; i < 48; i++) {
                part[i] += __shfl_xor(part[i], 1);
                part[i] += __shfl_xor(part[i], 2);
            }
            if ((kc & 3) == 0) {
#pragma unroll
                for (int rr = 0; rr < 12; rr++)
#pragma unroll
                    for (int bi = 0; bi < 4; bi++)
                        red[(rr * 16 + bg * 4 + bi) * 17 + (kc >> 2)] = part[rr * 4 + bi];
            }
        }
        __syncthreads();
        if (do1 && tid < 192) {
            float sm = 0.f;
#pragma unroll
            for (int c = 0; c < 16; c++) sm += red[tid * 17 + c];
            sums[tid] = sm;
        }
        __syncthreads();
        if (do1 && tid < 64) {
            float dr = sums[pjl * 16 + pb] + b1l[pjl];
            float dz = sums[(4 + pjl) * 16 + pb] + b1l[4 + pjl];
            float dn = sums[(8 + pjl) * 16 + pb] + b1l[8 + pjl];
            float r = 1.f / (1.f + expf(-(x1r + dr)));
            float z = 1.f / (1.f + expf(-(x1z + dz)));
            float n = tanhf(x1n + r * dn);
            float hv = (1.f - z) * n + z * hreg1;
            hreg1 = hv;
            store_f32_sc(ys1 + (size_t)(t1 * NB + pb) * FEAT + pj, hv);
            if (t1 == NT - 1) hid[NB * FEAT + pb * FEAT + pj] = hv;
        }

        // ================= barrier (one per chain step) =================
        unsigned expected = (unsigned)(s + 1);
        __syncthreads();
        if (tid == 0) {
            bar_arrive(&flags[wg * FLAG_STRIDE], expected);
            if (s + 1 < NT)
                bar_poll(&xpcnt[((s + 1) >> 3) * FLAG_STRIDE], NXPT);
            int t1n = s + 1 - DLY;
            if (t1n >= 0 && t1n < NT)
                bar_poll(&xp1cnt[(t1n >> 3) * FLAG_STRIDE], NXPT);
        }
        if (wg < NGRP) {
            if (tid < GSZ) bar_poll(flags + (wg * GSZ + tid) * FLAG_STRIDE, expected);
            if (tid == 0) {
                asm volatile("global_store_dword %0, %1, off sc0 sc1"
                             :: "v"(&gflags[wg * FLAG_STRIDE]), "v"(expected) : "memory");
            }
        }
        if (tid < NGRP) bar_poll(gflags + tid * FLAG_STRIDE, expected);
        __builtin_amdgcn_sched_barrier(0);
        __syncthreads();
    }
}

// ---- chain kernel: scan (0..255) || xp0 producers || gated xp1 producers ----
__global__ __launch_bounds__(256, 2) void chain_kernel(
        float* __restrict__ xp, const float* __restrict__ xs,
        const float* __restrict__ Whh0, const float* __restrict__ bhh0,
        const float* __restrict__ Wih0, const float* __restrict__ bih0,
        const float* __restrict__ Whh1, const float* __restrict__ bhh1,
        const float* __restrict__ Wih1, const float* __restrict__ bih1,
        const float* __restrict__ h0all,
        float* __restrict__ ys0, float* __restrict__ ys1,
        float* __restrict__ hid,
        unsigned* __restrict__ flags, unsigned* __restrict__ gflags,
        unsigned* __restrict__ xpcnt, unsigned* __restrict__ xp1cnt) {
    __shared__ __align__(16) char smem[SMEM_BYTES];
    int bid = blockIdx.x;
    if (bid < NWG) {
        scan_chain(smem, xp, Whh0, bhh0, Whh1, bhh1, h0all,
                   ys0, ys1, hid, flags, gflags, xpcnt, xp1cnt);
    } else if (bid < NWG + (4096 / 128) * NXPT) {
        // xp0 producers (ungated): coherent store + per-m counter
        int b2 = bid - NWG;
        int perGroup = 8 * NXPT;
        int g = b2 / perGroup, rix = b2 % perGroup;
        int n_t = rix / 8, m_t = g * 8 + (rix % 8);
        gemm_tile(smem, xs, Wih0, bih0, xp, G3, FEAT, m_t, n_t, 0,
                  1, &xpcnt[m_t * FLAG_STRIDE]);
    } else {
        // xp1 producers: gated on chain progress; in-place coherent rewrite
        int b2 = bid - NWG - (4096 / 128) * NXPT;
        int perGroup = 8 * NXPT;
        int g = b2 / perGroup, rix = b2 % perGroup;
        int n_t = rix / 8, m_t = g * 8 + (rix % 8);
        unsigned gate = (unsigned)((m_t + 1) * 8);
        if (threadIdx.x < NGRP) bar_poll(gflags + threadIdx.x * FLAG_STRIDE, gate);
        __builtin_amdgcn_sched_barrier(0);
        __syncthreads();
        gemm_tile(smem, ys0, Wih1, bih1, xp, G3, FEAT, m_t, n_t, 0,
                  1, &xp1cnt[m_t * FLAG_STRIDE]);
    }
}

// ---------------- launcher ----------------
extern "C" void kernel_launch(void* const* d_in, const int* in_sizes, int n_in,
                              void* d_out, int out_size, void* d_ws, size_t ws_size,
                              hipStream_t stream) {
    const int*   x     = (const int*)d_in[0];
    const float* h0    = (const float*)d_in[1];
    const float* emb   = (const float*)d_in[2];
    const float* W_ih0 = (const float*)d_in[3];
    const float* W_hh0 = (const float*)d_in[4];
    const float* b_ih0 = (const float*)d_in[5];
    const float* b_hh0 = (const float*)d_in[6];
    const float* W_ih1 = (const float*)d_in[7];
    const float* W_hh1 = (const float*)d_in[8];
    const float* b_ih1 = (const float*)d_in[9];
    const float* b_hh1 = (const float*)d_in[10];
    const float* dec_b = (const float*)d_in[11];

    float* out = (float*)d_out;
    float* hid_out = out + (size_t)NB * NT * VOCAB;

    float* ws  = (float*)d_ws;
    float* xp  = ws;                                    // [4096][3072] xp0 -> xp1
    float* xs  = xp + (size_t)4096 * 3072;              // gather out; ys1 ring
    float* ys0 = xs + (size_t)4096 * 1024;              // [4096][1024] ring
    float* pad = ys0 + (size_t)4096 * 1024;
    unsigned* flags  = (unsigned*)(pad + 2 * NB * FEAT);
    unsigned* gflags = flags + NWG * FLAG_STRIDE;
    unsigned* xpcnt  = gflags + NGRP * FLAG_STRIDE;     // 32 ctrs, 128B apart
    unsigned* xp1cnt = xpcnt + 32 * FLAG_STRIDE;        // 32 ctrs
    float* ys1 = xs;                                    // ring (xpcnt-ordered safe)

    // 0. zero barrier flags + counters
    hipMemsetAsync((void*)flags, 0,
                   (NWG + NGRP + 64) * FLAG_STRIDE * sizeof(unsigned), stream);

    // 1. gather
    gather_kernel<<<dim3(NT * NB), dim3(256), 0, stream>>>(x, emb, xs);

    // 2. combined chain: scan(L0+L1) || xp0 GEMM || gated xp1 GEMM
    chain_kernel<<<dim3(NWG + 2 * (4096 / 128) * NXPT), dim3(256), 0, stream>>>(
        xp, xs, W_hh0, b_hh0, W_ih0, b_ih0, W_hh1, b_hh1, W_ih1, b_ih1,
        h0, ys0, ys1, hid_out, flags, gflags, xpcnt, xp1cnt);

    // 3. tied decoder (serial — overlap proven value-destroying r14-16)
    gemm_split16<<<dim3((4096 / 128) * (VOCAB / 128)), dim3(256), 0, stream>>>(
        ys1, emb, dec_b, out, VOCAB, FEAT, 8, 1);
}